// Round 12
// baseline (265.425 us; speedup 1.0000x reference)
//
#include <hip/hip_runtime.h>
#include <hip/hip_bf16.h>
#include <stdint.h>

#define B_  32
#define T_  512
#define C_  1024
#define NH_ 16
#define DH_ 64

typedef __attribute__((ext_vector_type(8))) __bf16 bf16x8;
typedef __attribute__((ext_vector_type(4))) __bf16 bf16x4;
typedef __attribute__((ext_vector_type(4))) float  f32x4;

__device__ __forceinline__ void gload_lds16(const void* g, void* lds) {
  __builtin_amdgcn_global_load_lds(
      (const __attribute__((address_space(1))) void*)(uintptr_t)g,
      (__attribute__((address_space(3))) void*)(uint32_t)(uintptr_t)lds,
      16, 0, 0);
}

// ---------------- fused prep: casts + rope tables (one launch) ----------------
__global__ void prep_kernel(const float* __restrict__ x,
                            const float* __restrict__ Wq, const float* __restrict__ Wk,
                            const float* __restrict__ Wv, const float* __restrict__ Wo,
                            __bf16* __restrict__ xb, __bf16* __restrict__ wqkv,
                            __bf16* __restrict__ wob,
                            float* __restrict__ cosT, float* __restrict__ sinT) {
  int i = blockIdx.x * blockDim.x + threadIdx.x;
  if (i < 4194304) {
    f32x4 v = *(const f32x4*)(x + (size_t)i * 4);
    bf16x4 o;
    o[0] = (__bf16)v[0]; o[1] = (__bf16)v[1]; o[2] = (__bf16)v[2]; o[3] = (__bf16)v[3];
    *(bf16x4*)(xb + (size_t)i * 4) = o;
  } else if (i < 5242880) {
    int j = i - 4194304;
    int w = j >> 18, idx = j & 262143;
    const float* src = (w == 0) ? Wq : (w == 1) ? Wk : (w == 2) ? Wv : Wo;
    __bf16* dst = (w == 3) ? wob : wqkv + (size_t)w * 1048576;
    f32x4 v = *(const f32x4*)(src + (size_t)idx * 4);
    bf16x4 o;
    o[0] = (__bf16)v[0]; o[1] = (__bf16)v[1]; o[2] = (__bf16)v[2]; o[3] = (__bf16)v[3];
    *(bf16x4*)(dst + (size_t)idx * 4) = o;
  } else if (i < 5259264) {
    int j = i - 5242880;            // T_*32
    int t = j >> 5, f = j & 31;
    float inv = powf(10000.0f, -(float)(2 * f) / 64.0f);
    float fr = (float)t * inv;
    cosT[j] = cosf(fr);
    sinT[j] = sinf(fr);
  }
}

// ------------ 256x256 BK64 8-phase counted-vmcnt GEMM (QKV only, r11) --------
template <int MODE>
__global__ __launch_bounds__(512, 2) void gemm8(
    const __bf16* __restrict__ A,
    const __bf16* __restrict__ W0, const __bf16* __restrict__ W1, const __bf16* __restrict__ W2,
    __bf16* __restrict__ q, __bf16* __restrict__ k, __bf16* __restrict__ vt,
    float* __restrict__ outp) {
  extern __shared__ __bf16 lds[];
  const int K = C_;
  const int NH8 = 64;   // (K/64) tiles * 4 halves
  int tid = threadIdx.x;
  int lane = tid & 63, wave = tid >> 6;
  int ql = lane & 15, g = lane >> 4;
  int wr = wave >> 2, wc = wave & 3;

  constexpr int BNH = (MODE == 0) ? 6 : 2;   // bn per XCD (r6 L2-aware map)
  int bid = blockIdx.x;
  int xcd = bid & 7, local = bid >> 3;
  int bm = (xcd >> 1) * 16 + local / BNH;
  int bn = (xcd & 1) * BNH + local % BNH;

  const __bf16* Ag = A + (size_t)bm * 256 * K;
  const __bf16* Wg;
  if (MODE == 0) {
    int mat = bn >> 2;
    const __bf16* Wsel = (mat == 0) ? W0 : (mat == 1) ? W1 : W2;
    Wg = Wsel + (size_t)(bn & 3) * 256 * K;
  } else {
    Wg = W0 + (size_t)bn * 256 * K;
  }

  int schunk = (tid & 3) ^ ((tid >> 3) & 3);
  size_t stg_base = (size_t)(tid >> 2) * K + schunk * 8;

  int xsw = (g ^ ((ql >> 1) & 3)) * 8;
  int aoffW[8], boffW[4];
#pragma unroll
  for (int m = 0; m < 8; m++) aoffW[m] = (wr * 128 + m * 16 + ql) * 32 + xsw;
#pragma unroll
  for (int n = 0; n < 4; n++) boffW[n] = (wc * 64 + n * 16 + ql) * 32 + xsw;

#define STAGE_H(h)                                                          \
  if ((h) < NH8) {                                                          \
    int tl_ = (h) >> 2, pt_ = (h) & 3;                                      \
    const __bf16* s_ = ((pt_ & 1) ? Wg : Ag) + stg_base +                   \
                       (size_t)tl_ * 64 + (pt_ >> 1) * 32;                  \
    __bf16* d_ = lds + (((tl_ & 1) * 4 + pt_) * 8192) + tid * 8;            \
    gload_lds16(s_, d_);                                                    \
    gload_lds16(s_ + (size_t)128 * K, d_ + 4096);                           \
  }

#define PH(TP, KK, MLO, RB, SH, VM)                                         \
  {                                                                         \
    const __bf16* abase_ = lds + (((TP) * 4 + ((KK) ? 2 : 0)) * 8192);      \
    _Pragma("unroll")                                                       \
    for (int mm = 0; mm < 4; mm++)                                          \
      a[mm] = *(const bf16x8*)(abase_ + aoffW[(MLO) + mm]);                 \
    if (RB) {                                                               \
      const __bf16* bbase_ = lds + (((TP) * 4 + ((KK) ? 3 : 1)) * 8192);    \
      _Pragma("unroll")                                                     \
      for (int n = 0; n < 4; n++)                                           \
        b[n] = *(const bf16x8*)(bbase_ + boffW[n]);                         \
    }                                                                       \
    STAGE_H(SH);                                                            \
    __builtin_amdgcn_s_barrier();                                           \
    asm volatile("s_waitcnt lgkmcnt(0)" ::: "memory");                      \
    __builtin_amdgcn_sched_barrier(0);                                      \
    __builtin_amdgcn_s_setprio(1);                                          \
    _Pragma("unroll")                                                       \
    for (int mm = 0; mm < 4; mm++)                                          \
      _Pragma("unroll")                                                     \
      for (int n = 0; n < 4; n++)                                           \
        acc[(MLO) + mm][n] = __builtin_amdgcn_mfma_f32_16x16x32_bf16(       \
            a[mm], b[n], acc[(MLO) + mm][n], 0, 0, 0);                      \
    __builtin_amdgcn_s_setprio(0);                                          \
    {                                                                       \
      int vm_ = (VM);                                                       \
      if (vm_ == 0)      { asm volatile("s_waitcnt vmcnt(0)" ::: "memory"); } \
      else if (vm_ > 0)  { asm volatile("s_waitcnt vmcnt(6)" ::: "memory"); } \
    }                                                                       \
    __builtin_amdgcn_s_barrier();                                           \
  }

  STAGE_H(0); STAGE_H(1); STAGE_H(2); STAGE_H(3);
  STAGE_H(4); STAGE_H(5); STAGE_H(6);
  asm volatile("s_waitcnt vmcnt(6)" ::: "memory");
  __builtin_amdgcn_s_barrier();
  __builtin_amdgcn_sched_barrier(0);

  f32x4 acc[8][4] = {};
  bf16x8 a[4], b[4];
  for (int i = 0; i < 8; ++i) {
    int hb = 8 * i;
    int vm4 = (i == 7) ? 0 : 6;
    int vm8 = (i == 7) ? -1 : 6;
    PH(0, 0, 0, 1, hb + 7,  -1)
    PH(0, 0, 4, 0, hb + 8,  -1)
    PH(0, 1, 0, 1, hb + 9,  -1)
    PH(0, 1, 4, 0, hb + 10, vm4)
    PH(1, 0, 0, 1, hb + 11, -1)
    PH(1, 0, 4, 0, hb + 12, -1)
    PH(1, 1, 0, 1, hb + 13, -1)
    PH(1, 1, 4, 0, hb + 14, vm8)
  }
#undef PH
#undef STAGE_H

  int r0 = bm * 256 + wr * 128;
  int c0 = bn * 256 + wc * 64;
  if (MODE == 0) {
    int mat = c0 >> 10;  // block-uniform
#pragma unroll
    for (int m = 0; m < 8; m++) {
      int row = r0 + m * 16 + g * 4;
      int bb = row >> 9, tt = row & 511;
#pragma unroll
      for (int n = 0; n < 4; n++) {
        int col = c0 + n * 16 + ql;
        int h = (col & 1023) >> 6, d = col & 63;
        if (mat == 2) {
          bf16x4 ov;
#pragma unroll
          for (int r = 0; r < 4; r++) ov[r] = (__bf16)acc[m][n][r];
          *(bf16x4*)(vt + ((size_t)(bb * NH_ + h) * DH_ + d) * T_ + tt) = ov;
        } else {
          __bf16* dst = (mat == 0 ? q : k) + ((size_t)(bb * NH_ + h) * T_ + tt) * DH_ + d;
#pragma unroll
          for (int r = 0; r < 4; r++) dst[r * DH_] = (__bf16)acc[m][n][r];
        }
      }
    }
  } else {
#pragma unroll
    for (int m = 0; m < 8; m++) {
      int row = r0 + m * 16 + g * 4;
#pragma unroll
      for (int r = 0; r < 4; r++)
#pragma unroll
        for (int n = 0; n < 4; n++)
          outp[(size_t)(row + r) * C_ + c0 + n * 16 + ql] = acc[m][n][r];
    }
  }
}

// ------------ out-proj: 128x128 BK64 m97-structure GEMM, multi-block/CU ------
// out[m,n] = sum_k A[m,k]*W[n,k]; f32 out. Grid 1024 blocks (4-5 co-resident
// per CU -> inter-block overlap hides barrier drains, m97 mechanism).
// Chunk-XOR swizzle: physical 16B-chunk p of row r holds logical chunk
// p^(r&7); source pre-swizzled (linear gload_lds dest), ds_read applies XOR.
// XCD map: XCD x owns bm in [16x,16x+16), all 8 bn (W = 2MB stays L2-hot).
__global__ __launch_bounds__(256) void gemm_op(
    const __bf16* __restrict__ A, const __bf16* __restrict__ W,
    float* __restrict__ outp) {
  __shared__ __bf16 As[128 * 64];
  __shared__ __bf16 Bs[128 * 64];
  const int K = C_;
  int tid = threadIdx.x;
  int lane = tid & 63, wave = tid >> 6;
  int ql = lane & 15, g = lane >> 4;
  int wr = wave >> 1, wc = wave & 1;

  int xcd = blockIdx.x & 7, local = blockIdx.x >> 3;  // local 0..127
  int bm = xcd * 16 + (local >> 3);
  int bn = local & 7;

  int srow = tid >> 3;          // 0..31
  int cphys = tid & 7;
  int clog = cphys ^ (srow & 7);
  const __bf16* Ab = A + (size_t)(bm * 128 + srow) * K + clog * 8;
  const __bf16* Wb = W + (size_t)(bn * 128 + srow) * K + clog * 8;
  __bf16* AsP = &As[srow * 64 + cphys * 8];
  __bf16* BsP = &Bs[srow * 64 + cphys * 8];

  int xk = ql & 7;
  f32x4 acc[4][4] = {};
  for (int k0 = 0; k0 < K; k0 += 64) {
#pragma unroll
    for (int i = 0; i < 4; i++) gload_lds16(Ab + (size_t)i * 32 * K + k0, AsP + i * 2048);
#pragma unroll
    for (int i = 0; i < 4; i++) gload_lds16(Wb + (size_t)i * 32 * K + k0, BsP + i * 2048);
    __syncthreads();
#pragma unroll
    for (int kk = 0; kk < 2; kk++) {
      bf16x8 a[4], b[4];
#pragma unroll
      for (int m = 0; m < 4; m++)
        a[m] = *(const bf16x8*)&As[(wr * 64 + m * 16 + ql) * 64 + (((kk * 4 + g) ^ xk) * 8)];
#pragma unroll
      for (int n = 0; n < 4; n++)
        b[n] = *(const bf16x8*)&Bs[(wc * 64 + n * 16 + ql) * 64 + (((kk * 4 + g) ^ xk) * 8)];
#pragma unroll
      for (int m = 0; m < 4; m++)
#pragma unroll
        for (int n = 0; n < 4; n++)
          acc[m][n] = __builtin_amdgcn_mfma_f32_16x16x32_bf16(a[m], b[n], acc[m][n], 0, 0, 0);
    }
    __syncthreads();
  }

  int r0 = bm * 128 + wr * 64;
  int c0 = bn * 128 + wc * 64;
#pragma unroll
  for (int m = 0; m < 4; m++) {
    int row = r0 + m * 16 + g * 4;
#pragma unroll
    for (int r = 0; r < 4; r++)
#pragma unroll
      for (int n = 0; n < 4; n++)
        outp[(size_t)(row + r) * C_ + c0 + n * 16 + ql] = acc[m][n][r];
  }
}

// ---------------- flash attention: LDS-resident K/V, rope fused --------------
// r8-verified structure; r12: V staged via global_load_lds (one wave-instr per
// 1KB row, even-key 16B-chunk XOR swizzle chunk^(d&7) — pre-swizzled source,
// linear lane dest; read applies same XOR). LDS now exactly 128 KiB.
__global__ __launch_bounds__(512, 2) void attn_kernel(
    const __bf16* __restrict__ qg, const __bf16* __restrict__ kg,
    const __bf16* __restrict__ vg, __bf16* __restrict__ ao,
    const float* __restrict__ cosT, const float* __restrict__ sinT) {
  extern __shared__ char smem[];
  __bf16* Klds = (__bf16*)smem;              // [512][64], chunk-XOR swizzled
  __bf16* Vlds = (__bf16*)(smem + 65536);    // [64][512], chunk-XOR swizzled

  int tid = threadIdx.x;
  int lane = tid & 63, wave = tid >> 6;
  int ql = lane & 15, g = lane >> 4;
  int bh = blockIdx.x;
  int b = bh >> 4, h = bh & 15;
  const __bf16* qp = qg + (size_t)bh * (T_ * DH_);
  const __bf16* kp = kg + (size_t)bh * (T_ * DH_);
  const __bf16* vp = vg + (size_t)bh * (T_ * DH_);  // [DH][T]

  // ---- stage V^T via gload_lds (async; key = d&7 = wave, even 16B units) ----
#pragma unroll
  for (int i = 0; i < 8; i++) {
    int d = i * 8 + wave;                  // d&7 == wave
    const __bf16* src = vp + (size_t)d * T_ + ((lane ^ wave) * 8);
    gload_lds16(src, Vlds + d * 512 + lane * 8);
  }

  // ---- stage K (with rope, reg-staged) ----
  {
    int cb = tid & 7;       // 16B chunk within row
    int rb = tid >> 3;      // row base 0..63
#pragma unroll
    for (int i = 0; i < 8; i++) {
      int row = rb + i * 64;
      bf16x8 raw = *(const bf16x8*)(kp + (size_t)row * DH_ + cb * 8);
      f32x4 c4 = *(const f32x4*)(cosT + row * 32 + cb * 4);
      f32x4 s4 = *(const f32x4*)(sinT + row * 32 + cb * 4);
      bf16x8 out;
#pragma unroll
      for (int p = 0; p < 4; p++) {
        float a0 = (float)raw[2 * p], a1 = (float)raw[2 * p + 1];
        out[2 * p]     = (__bf16)(a0 * c4[p] - a1 * s4[p]);
        out[2 * p + 1] = (__bf16)(a0 * s4[p] + a1 * c4[p]);
      }
      *(bf16x8*)(Klds + row * 64 + ((cb ^ (row & 7)) * 8)) = out;
    }
  }

  // ---- load + rope Q (scale 1/8) while staging lands ----
  int q0 = wave * 64;
  bf16x8 qf[4][2];
#pragma unroll
  for (int s = 0; s < 4; s++)
#pragma unroll
    for (int kk = 0; kk < 2; kk++) {
      int tq = q0 + s * 16 + ql;
      bf16x8 raw = *(const bf16x8*)(qp + (size_t)tq * DH_ + kk * 32 + g * 8);
      int fb = tq * 32 + kk * 16 + g * 4;
      f32x4 c4 = *(const f32x4*)(cosT + fb);
      f32x4 s4 = *(const f32x4*)(sinT + fb);
      bf16x8 out;
#pragma unroll
      for (int p = 0; p < 4; p++) {
        float a0 = (float)raw[2 * p], a1 = (float)raw[2 * p + 1];
        out[2 * p]     = (__bf16)(0.125f * (a0 * c4[p] - a1 * s4[p]));
        out[2 * p + 1] = (__bf16)(0.125f * (a0 * s4[p] + a1 * c4[p]));
      }
      qf[s][kk] = out;
    }

  __syncthreads();   // waits vmcnt(0) + lgkmcnt(0): V gload_lds + K writes land

  f32x4 o[4][4] = {};
  float mrow[4] = {-1e30f, -1e30f, -1e30f, -1e30f};
  float lrow[4] = {0.f, 0.f, 0.f, 0.f};

  for (int kv0 = 0; kv0 < T_; kv0 += 32) {
    bf16x8 kf[2][2], vf[4];
#pragma unroll
    for (int sub = 0; sub < 2; sub++)
#pragma unroll
      for (int kk = 0; kk < 2; kk++) {
        int t = kv0 + sub * 16 + ql;
        int cc = kk * 4 + g;
        kf[sub][kk] = *(const bf16x8*)(Klds + t * 64 + ((cc ^ (t & 7)) * 8));
      }
#pragma unroll
    for (int c = 0; c < 4; c++) {
      int d = c * 16 + ql;
      int key = ql & 7;                       // d&7
      const __bf16* vb = Vlds + d * 512;
      int chlo = ((kv0 >> 3) + (g >> 1)) ^ key;
      int chhi = (((kv0 + 16) >> 3) + (g >> 1)) ^ key;
      bf16x4 vlo = *(const bf16x4*)(vb + chlo * 8 + (g & 1) * 4);
      bf16x4 vhi = *(const bf16x4*)(vb + chhi * 8 + (g & 1) * 4);
#pragma unroll
      for (int r = 0; r < 4; r++) { vf[c][r] = vlo[r]; vf[c][4 + r] = vhi[r]; }
    }

#pragma unroll
    for (int s = 0; s < 4; s++) {
      f32x4 s0 = {0.f, 0.f, 0.f, 0.f}, s1 = {0.f, 0.f, 0.f, 0.f};
      __builtin_amdgcn_s_setprio(1);
#pragma unroll
      for (int kk = 0; kk < 2; kk++) {
        s0 = __builtin_amdgcn_mfma_f32_16x16x32_bf16(kf[0][kk], qf[s][kk], s0, 0, 0, 0);
        s1 = __builtin_amdgcn_mfma_f32_16x16x32_bf16(kf[1][kk], qf[s][kk], s1, 0, 0, 0);
      }
      __builtin_amdgcn_s_setprio(0);
      float tm = s0[0];
#pragma unroll
      for (int r = 1; r < 4; r++) tm = fmaxf(tm, s0[r]);
#pragma unroll
      for (int r = 0; r < 4; r++) tm = fmaxf(tm, s1[r]);
      tm = fmaxf(tm, __shfl_xor(tm, 16));
      tm = fmaxf(tm, __shfl_xor(tm, 32));
      if (!__all(tm <= mrow[s] + 8.0f)) {
        float mnew = fmaxf(mrow[s], tm);
        float corr = __expf(mrow[s] - mnew);
        mrow[s] = mnew;
        lrow[s] *= corr;
#pragma unroll
        for (int c = 0; c < 4; c++) o[s][c] *= corr;
      }
      float p0[4], p1[4], ps = 0.f;
#pragma unroll
      for (int r = 0; r < 4; r++) {
        p0[r] = __expf(s0[r] - mrow[s]);
        p1[r] = __expf(s1[r] - mrow[s]);
        ps += p0[r] + p1[r];
      }
      ps += __shfl_xor(ps, 16);
      ps += __shfl_xor(ps, 32);
      lrow[s] += ps;
      bf16x8 pb;
#pragma unroll
      for (int r = 0; r < 4; r++) {
        pb[r]     = (__bf16)p0[r];
        pb[4 + r] = (__bf16)p1[r];
      }
      __builtin_amdgcn_s_setprio(1);
#pragma unroll
      for (int c = 0; c < 4; c++)
        o[s][c] = __builtin_amdgcn_mfma_f32_16x16x32_bf16(vf[c], pb, o[s][c], 0, 0, 0);
      __builtin_amdgcn_s_setprio(0);
    }
  }

#pragma unroll
  for (int s = 0; s < 4; s++) {
    float inv = 1.0f / lrow[s];
    size_t row = (size_t)b * T_ + q0 + s * 16 + ql;
    size_t baseo = row * C_ + h * DH_;
#pragma unroll
    for (int c = 0; c < 4; c++) {
      bf16x4 ov;
#pragma unroll
      for (int r = 0; r < 4; r++) ov[r] = (__bf16)(o[s][c][r] * inv);
      *(bf16x4*)(ao + baseo + c * 16 + g * 4) = ov;
    }
  }
}

extern "C" void kernel_launch(void* const* d_in, const int* in_sizes, int n_in,
                              void* d_out, int out_size, void* d_ws, size_t ws_size,
                              hipStream_t stream) {
  (void)in_sizes; (void)n_in; (void)out_size; (void)ws_size;
  const float* x  = (const float*)d_in[0];
  const float* Wq = (const float*)d_in[1];
  const float* Wk = (const float*)d_in[2];
  const float* Wv = (const float*)d_in[3];
  const float* Wo = (const float*)d_in[4];

  char* ws = (char*)d_ws;
  char* od = (char*)d_out;
  float* outp = (float*)d_out;

  // d_out hosts qb+kb (raw, un-roped; 32 MiB each); dead before out-proj overwrites.
  __bf16* qb = (__bf16*)(od);
  __bf16* kb = (__bf16*)(od + 33554432);
  // ws: xb/aob @0 (32M), vtb @32M (32M), wqkv @64M (6M), wob @70M (2M), tables @72M
  __bf16* xb   = (__bf16*)(ws);
  __bf16* vtb  = (__bf16*)(ws + 33554432);
  __bf16* wqkv = (__bf16*)(ws + 67108864);
  __bf16* wob  = (__bf16*)(ws + 73400320);
  float*  cosT = (float*)(ws + 75497472);
  float*  sinT = (float*)(ws + 75563008);
  __bf16* aob  = xb;  // x dead after QKV GEMM

  auto k0 = gemm8<0>;
  hipFuncSetAttribute((const void*)k0, hipFuncAttributeMaxDynamicSharedMemorySize, 131072);
  hipFuncSetAttribute((const void*)attn_kernel, hipFuncAttributeMaxDynamicSharedMemorySize, 131072);

  // 1) fused casts + rope tables
  prep_kernel<<<dim3(20544), dim3(256), 0, stream>>>(
      x, Wq, Wk, Wv, Wo, xb, wqkv, wob, cosT, sinT);

  // 2) QKV: M=16384, N=3072 -> 768 blocks (8-phase BK64, r11 best)
  gemm8<0><<<dim3(768), dim3(512), 131072, stream>>>(
      xb, wqkv, wqkv + 1048576, wqkv + 2097152, qb, kb, vtb, nullptr);

  // 3) attention (LDS-resident K/V, fused rope, async V stage)
  attn_kernel<<<dim3(B_ * NH_), dim3(512), 131072, stream>>>(
      qb, kb, vtb, aob, cosT, sinT);

  // 4) out-proj: 128^2 tile, grid 1024 (4-5 blocks/CU inter-block overlap)
  gemm_op<<<dim3(1024), dim3(256), 0, stream>>>(aob, wob, outp);
}

// Round 13
// 245.287 us; speedup vs baseline: 1.0821x; 1.0821x over previous
//
#include <hip/hip_runtime.h>
#include <hip/hip_bf16.h>
#include <stdint.h>

#define B_  32
#define T_  512
#define C_  1024
#define NH_ 16
#define DH_ 64

typedef __attribute__((ext_vector_type(8))) __bf16 bf16x8;
typedef __attribute__((ext_vector_type(4))) __bf16 bf16x4;
typedef __attribute__((ext_vector_type(4))) float  f32x4;

__device__ __forceinline__ void gload_lds16(const void* g, void* lds) {
  __builtin_amdgcn_global_load_lds(
      (const __attribute__((address_space(1))) void*)(uintptr_t)g,
      (__attribute__((address_space(3))) void*)(uint32_t)(uintptr_t)lds,
      16, 0, 0);
}

// ---------------- fused prep: casts + rope tables (one launch) ----------------
__global__ void prep_kernel(const float* __restrict__ x,
                            const float* __restrict__ Wq, const float* __restrict__ Wk,
                            const float* __restrict__ Wv, const float* __restrict__ Wo,
                            __bf16* __restrict__ xb, __bf16* __restrict__ wqkv,
                            __bf16* __restrict__ wob,
                            float* __restrict__ cosT, float* __restrict__ sinT) {
  int i = blockIdx.x * blockDim.x + threadIdx.x;
  if (i < 4194304) {
    f32x4 v = *(const f32x4*)(x + (size_t)i * 4);
    bf16x4 o;
    o[0] = (__bf16)v[0]; o[1] = (__bf16)v[1]; o[2] = (__bf16)v[2]; o[3] = (__bf16)v[3];
    *(bf16x4*)(xb + (size_t)i * 4) = o;
  } else if (i < 5242880) {
    int j = i - 4194304;
    int w = j >> 18, idx = j & 262143;
    const float* src = (w == 0) ? Wq : (w == 1) ? Wk : (w == 2) ? Wv : Wo;
    __bf16* dst = (w == 3) ? wob : wqkv + (size_t)w * 1048576;
    f32x4 v = *(const f32x4*)(src + (size_t)idx * 4);
    bf16x4 o;
    o[0] = (__bf16)v[0]; o[1] = (__bf16)v[1]; o[2] = (__bf16)v[2]; o[3] = (__bf16)v[3];
    *(bf16x4*)(dst + (size_t)idx * 4) = o;
  } else if (i < 5259264) {
    int j = i - 5242880;            // T_*32
    int t = j >> 5, f = j & 31;
    float inv = powf(10000.0f, -(float)(2 * f) / 64.0f);
    float fr = (float)t * inv;
    cosT[j] = cosf(fr);
    sinT[j] = sinf(fr);
  }
}

// ------------ 256x256 BK64 8-phase counted-vmcnt GEMM (r11, measured best) ---
template <int MODE>
__global__ __launch_bounds__(512, 2) void gemm8(
    const __bf16* __restrict__ A,
    const __bf16* __restrict__ W0, const __bf16* __restrict__ W1, const __bf16* __restrict__ W2,
    __bf16* __restrict__ q, __bf16* __restrict__ k, __bf16* __restrict__ vt,
    float* __restrict__ outp) {
  extern __shared__ __bf16 lds[];
  const int K = C_;
  const int NH8 = 64;   // (K/64) tiles * 4 halves
  int tid = threadIdx.x;
  int lane = tid & 63, wave = tid >> 6;
  int ql = lane & 15, g = lane >> 4;
  int wr = wave >> 2, wc = wave & 3;

  constexpr int BNH = (MODE == 0) ? 6 : 2;   // bn per XCD (r6 L2-aware map)
  int bid = blockIdx.x;
  int xcd = bid & 7, local = bid >> 3;
  int bm = (xcd >> 1) * 16 + local / BNH;
  int bn = (xcd & 1) * BNH + local % BNH;

  const __bf16* Ag = A + (size_t)bm * 256 * K;
  const __bf16* Wg;
  if (MODE == 0) {
    int mat = bn >> 2;
    const __bf16* Wsel = (mat == 0) ? W0 : (mat == 1) ? W1 : W2;
    Wg = Wsel + (size_t)(bn & 3) * 256 * K;
  } else {
    Wg = W0 + (size_t)bn * 256 * K;
  }

  int schunk = (tid & 3) ^ ((tid >> 3) & 3);
  size_t stg_base = (size_t)(tid >> 2) * K + schunk * 8;

  int xsw = (g ^ ((ql >> 1) & 3)) * 8;
  int aoffW[8], boffW[4];
#pragma unroll
  for (int m = 0; m < 8; m++) aoffW[m] = (wr * 128 + m * 16 + ql) * 32 + xsw;
#pragma unroll
  for (int n = 0; n < 4; n++) boffW[n] = (wc * 64 + n * 16 + ql) * 32 + xsw;

#define STAGE_H(h)                                                          \
  if ((h) < NH8) {                                                          \
    int tl_ = (h) >> 2, pt_ = (h) & 3;                                      \
    const __bf16* s_ = ((pt_ & 1) ? Wg : Ag) + stg_base +                   \
                       (size_t)tl_ * 64 + (pt_ >> 1) * 32;                  \
    __bf16* d_ = lds + (((tl_ & 1) * 4 + pt_) * 8192) + tid * 8;            \
    gload_lds16(s_, d_);                                                    \
    gload_lds16(s_ + (size_t)128 * K, d_ + 4096);                           \
  }

#define PH(TP, KK, MLO, RB, SH, VM)                                         \
  {                                                                         \
    const __bf16* abase_ = lds + (((TP) * 4 + ((KK) ? 2 : 0)) * 8192);      \
    _Pragma("unroll")                                                       \
    for (int mm = 0; mm < 4; mm++)                                          \
      a[mm] = *(const bf16x8*)(abase_ + aoffW[(MLO) + mm]);                 \
    if (RB) {                                                               \
      const __bf16* bbase_ = lds + (((TP) * 4 + ((KK) ? 3 : 1)) * 8192);    \
      _Pragma("unroll")                                                     \
      for (int n = 0; n < 4; n++)                                           \
        b[n] = *(const bf16x8*)(bbase_ + boffW[n]);                         \
    }                                                                       \
    STAGE_H(SH);                                                            \
    __builtin_amdgcn_s_barrier();                                           \
    asm volatile("s_waitcnt lgkmcnt(0)" ::: "memory");                      \
    __builtin_amdgcn_sched_barrier(0);                                      \
    __builtin_amdgcn_s_setprio(1);                                          \
    _Pragma("unroll")                                                       \
    for (int mm = 0; mm < 4; mm++)                                          \
      _Pragma("unroll")                                                     \
      for (int n = 0; n < 4; n++)                                           \
        acc[(MLO) + mm][n] = __builtin_amdgcn_mfma_f32_16x16x32_bf16(       \
            a[mm], b[n], acc[(MLO) + mm][n], 0, 0, 0);                      \
    __builtin_amdgcn_s_setprio(0);                                          \
    {                                                                       \
      int vm_ = (VM);                                                       \
      if (vm_ == 0)      { asm volatile("s_waitcnt vmcnt(0)" ::: "memory"); } \
      else if (vm_ > 0)  { asm volatile("s_waitcnt vmcnt(6)" ::: "memory"); } \
    }                                                                       \
    __builtin_amdgcn_s_barrier();                                           \
  }

  STAGE_H(0); STAGE_H(1); STAGE_H(2); STAGE_H(3);
  STAGE_H(4); STAGE_H(5); STAGE_H(6);
  asm volatile("s_waitcnt vmcnt(6)" ::: "memory");
  __builtin_amdgcn_s_barrier();
  __builtin_amdgcn_sched_barrier(0);

  f32x4 acc[8][4] = {};
  bf16x8 a[4], b[4];
  for (int i = 0; i < 8; ++i) {
    int hb = 8 * i;
    int vm4 = (i == 7) ? 0 : 6;
    int vm8 = (i == 7) ? -1 : 6;
    PH(0, 0, 0, 1, hb + 7,  -1)
    PH(0, 0, 4, 0, hb + 8,  -1)
    PH(0, 1, 0, 1, hb + 9,  -1)
    PH(0, 1, 4, 0, hb + 10, vm4)
    PH(1, 0, 0, 1, hb + 11, -1)
    PH(1, 0, 4, 0, hb + 12, -1)
    PH(1, 1, 0, 1, hb + 13, -1)
    PH(1, 1, 4, 0, hb + 14, vm8)
  }
#undef PH
#undef STAGE_H

  int r0 = bm * 256 + wr * 128;
  int c0 = bn * 256 + wc * 64;
  if (MODE == 0) {
    int mat = c0 >> 10;  // block-uniform
#pragma unroll
    for (int m = 0; m < 8; m++) {
      int row = r0 + m * 16 + g * 4;
      int bb = row >> 9, tt = row & 511;
#pragma unroll
      for (int n = 0; n < 4; n++) {
        int col = c0 + n * 16 + ql;
        int h = (col & 1023) >> 6, d = col & 63;
        if (mat == 2) {
          bf16x4 ov;
#pragma unroll
          for (int r = 0; r < 4; r++) ov[r] = (__bf16)acc[m][n][r];
          *(bf16x4*)(vt + ((size_t)(bb * NH_ + h) * DH_ + d) * T_ + tt) = ov;
        } else {
          __bf16* dst = (mat == 0 ? q : k) + ((size_t)(bb * NH_ + h) * T_ + tt) * DH_ + d;
#pragma unroll
          for (int r = 0; r < 4; r++) dst[r * DH_] = (__bf16)acc[m][n][r];
        }
      }
    }
  } else {
#pragma unroll
    for (int m = 0; m < 8; m++) {
      int row = r0 + m * 16 + g * 4;
#pragma unroll
      for (int r = 0; r < 4; r++)
#pragma unroll
        for (int n = 0; n < 4; n++)
          outp[(size_t)(row + r) * C_ + c0 + n * 16 + ql] = acc[m][n][r];
    }
  }
}

// ---------------- flash attention: LDS-resident K/V, BATCHED inner loop -----
// r11 memory layout (K XOR-swizzled [512][64], V padded [64][516], reg-staged)
// r13: inner loop restructured for ILP — all 16 QK MFMAs, then softmax
// vectorized across the 4 independent s-chains, ONE __any-gated rescale
// branch per kv-tile (same online-softmax identity), then all 16 PV MFMAs.
__global__ __launch_bounds__(512, 2) void attn_kernel(
    const __bf16* __restrict__ qg, const __bf16* __restrict__ kg,
    const __bf16* __restrict__ vg, __bf16* __restrict__ ao,
    const float* __restrict__ cosT, const float* __restrict__ sinT) {
  extern __shared__ char smem[];
  __bf16* Klds = (__bf16*)smem;              // [512][64], chunk-XOR swizzled
  __bf16* Vlds = (__bf16*)(smem + 65536);    // [64][516] padded

  int tid = threadIdx.x;
  int lane = tid & 63, wave = tid >> 6;
  int ql = lane & 15, g = lane >> 4;
  int bh = blockIdx.x;
  int b = bh >> 4, h = bh & 15;
  const __bf16* qp = qg + (size_t)bh * (T_ * DH_);
  const __bf16* kp = kg + (size_t)bh * (T_ * DH_);
  const __bf16* vp = vg + (size_t)bh * (T_ * DH_);  // [DH][T]

  // ---- stage K (with rope) ----
  {
    int cb = tid & 7;       // 16B chunk within row
    int rb = tid >> 3;      // row base 0..63
#pragma unroll
    for (int i = 0; i < 8; i++) {
      int row = rb + i * 64;
      bf16x8 raw = *(const bf16x8*)(kp + (size_t)row * DH_ + cb * 8);
      f32x4 c4 = *(const f32x4*)(cosT + row * 32 + cb * 4);
      f32x4 s4 = *(const f32x4*)(sinT + row * 32 + cb * 4);
      bf16x8 out;
#pragma unroll
      for (int p = 0; p < 4; p++) {
        float a0 = (float)raw[2 * p], a1 = (float)raw[2 * p + 1];
        out[2 * p]     = (__bf16)(a0 * c4[p] - a1 * s4[p]);
        out[2 * p + 1] = (__bf16)(a0 * s4[p] + a1 * c4[p]);
      }
      *(bf16x8*)(Klds + row * 64 + ((cb ^ (row & 7)) * 8)) = out;
    }
  }
  // ---- stage V^T (linear, padded rows) ----
  {
    int d = tid >> 3;
    int cb = tid & 7;
    const __bf16* vrow = vp + (size_t)d * T_;
#pragma unroll
    for (int i = 0; i < 8; i++) {
      int c8 = cb + i * 8;     // 16B chunk 0..63 within row
      bf16x8 raw = *(const bf16x8*)(vrow + c8 * 8);
      *(bf16x8*)(Vlds + d * 516 + c8 * 8) = raw;
    }
  }

  // ---- load + rope Q (scale 1/8) while staging lands ----
  int q0 = wave * 64;
  bf16x8 qf[4][2];
#pragma unroll
  for (int s = 0; s < 4; s++)
#pragma unroll
    for (int kk = 0; kk < 2; kk++) {
      int tq = q0 + s * 16 + ql;
      bf16x8 raw = *(const bf16x8*)(qp + (size_t)tq * DH_ + kk * 32 + g * 8);
      int fb = tq * 32 + kk * 16 + g * 4;
      f32x4 c4 = *(const f32x4*)(cosT + fb);
      f32x4 s4 = *(const f32x4*)(sinT + fb);
      bf16x8 out;
#pragma unroll
      for (int p = 0; p < 4; p++) {
        float a0 = (float)raw[2 * p], a1 = (float)raw[2 * p + 1];
        out[2 * p]     = (__bf16)(0.125f * (a0 * c4[p] - a1 * s4[p]));
        out[2 * p + 1] = (__bf16)(0.125f * (a0 * s4[p] + a1 * c4[p]));
      }
      qf[s][kk] = out;
    }

  __syncthreads();

  f32x4 o[4][4] = {};
  float mrow[4] = {-1e30f, -1e30f, -1e30f, -1e30f};
  float lrow[4] = {0.f, 0.f, 0.f, 0.f};

  for (int kv0 = 0; kv0 < T_; kv0 += 32) {
    bf16x8 kf[2][2], vf[4];
#pragma unroll
    for (int sub = 0; sub < 2; sub++)
#pragma unroll
      for (int kk = 0; kk < 2; kk++) {
        int t = kv0 + sub * 16 + ql;
        int cc = kk * 4 + g;
        kf[sub][kk] = *(const bf16x8*)(Klds + t * 64 + ((cc ^ (t & 7)) * 8));
      }
#pragma unroll
    for (int c = 0; c < 4; c++) {
      int d = c * 16 + ql;
      bf16x4 vlo = *(const bf16x4*)(Vlds + d * 516 + kv0 + g * 4);
      bf16x4 vhi = *(const bf16x4*)(Vlds + d * 516 + kv0 + 16 + g * 4);
#pragma unroll
      for (int r = 0; r < 4; r++) { vf[c][r] = vlo[r]; vf[c][4 + r] = vhi[r]; }
    }

    // ---- 1) QK^T for ALL s (one MFMA region) ----
    f32x4 sa[4], sb[4];
    __builtin_amdgcn_s_setprio(1);
#pragma unroll
    for (int s = 0; s < 4; s++) {
      sa[s] = (f32x4){0.f, 0.f, 0.f, 0.f};
      sb[s] = (f32x4){0.f, 0.f, 0.f, 0.f};
#pragma unroll
      for (int kk = 0; kk < 2; kk++) {
        sa[s] = __builtin_amdgcn_mfma_f32_16x16x32_bf16(kf[0][kk], qf[s][kk], sa[s], 0, 0, 0);
        sb[s] = __builtin_amdgcn_mfma_f32_16x16x32_bf16(kf[1][kk], qf[s][kk], sb[s], 0, 0, 0);
      }
    }
    __builtin_amdgcn_s_setprio(0);

    // ---- 2) tile max per s, vectorized across s ----
    float tm[4];
#pragma unroll
    for (int s = 0; s < 4; s++) {
      float t0 = fmaxf(fmaxf(sa[s][0], sa[s][1]), fmaxf(sa[s][2], sa[s][3]));
      float t1 = fmaxf(fmaxf(sb[s][0], sb[s][1]), fmaxf(sb[s][2], sb[s][3]));
      tm[s] = fmaxf(t0, t1);
    }
#pragma unroll
    for (int s = 0; s < 4; s++) tm[s] = fmaxf(tm[s], __shfl_xor(tm[s], 16));
#pragma unroll
    for (int s = 0; s < 4; s++) tm[s] = fmaxf(tm[s], __shfl_xor(tm[s], 32));

    // ---- 3) single deferred-rescale branch (THR=8, exact math) ----
    bool need = (tm[0] > mrow[0] + 8.f) | (tm[1] > mrow[1] + 8.f) |
                (tm[2] > mrow[2] + 8.f) | (tm[3] > mrow[3] + 8.f);
    if (__any(need)) {
#pragma unroll
      for (int s = 0; s < 4; s++) {
        float mnew = fmaxf(mrow[s], tm[s]);
        float corr = __expf(mrow[s] - mnew);
        mrow[s] = mnew;
        lrow[s] *= corr;
#pragma unroll
        for (int c = 0; c < 4; c++) o[s][c] *= corr;
      }
    }

    // ---- 4) exp in place + row sums, vectorized across s ----
    float ps[4];
#pragma unroll
    for (int s = 0; s < 4; s++) {
#pragma unroll
      for (int r = 0; r < 4; r++) {
        sa[s][r] = __expf(sa[s][r] - mrow[s]);
        sb[s][r] = __expf(sb[s][r] - mrow[s]);
      }
      ps[s] = ((sa[s][0] + sa[s][1]) + (sa[s][2] + sa[s][3])) +
              ((sb[s][0] + sb[s][1]) + (sb[s][2] + sb[s][3]));
    }
#pragma unroll
    for (int s = 0; s < 4; s++) ps[s] += __shfl_xor(ps[s], 16);
#pragma unroll
    for (int s = 0; s < 4; s++) { ps[s] += __shfl_xor(ps[s], 32); lrow[s] += ps[s]; }

    // ---- 5) P->bf16 + ALL 16 PV MFMAs (one region) ----
    bf16x8 pb[4];
#pragma unroll
    for (int s = 0; s < 4; s++)
#pragma unroll
      for (int r = 0; r < 4; r++) {
        pb[s][r]     = (__bf16)sa[s][r];
        pb[s][4 + r] = (__bf16)sb[s][r];
      }
    __builtin_amdgcn_s_setprio(1);
#pragma unroll
    for (int s = 0; s < 4; s++)
#pragma unroll
      for (int c = 0; c < 4; c++)
        o[s][c] = __builtin_amdgcn_mfma_f32_16x16x32_bf16(vf[c], pb[s], o[s][c], 0, 0, 0);
    __builtin_amdgcn_s_setprio(0);
  }

#pragma unroll
  for (int s = 0; s < 4; s++) {
    float inv = 1.0f / lrow[s];
    size_t row = (size_t)b * T_ + q0 + s * 16 + ql;
    size_t baseo = row * C_ + h * DH_;
#pragma unroll
    for (int c = 0; c < 4; c++) {
      bf16x4 ov;
#pragma unroll
      for (int r = 0; r < 4; r++) ov[r] = (__bf16)(o[s][c][r] * inv);
      *(bf16x4*)(ao + baseo + c * 16 + g * 4) = ov;
    }
  }
}

extern "C" void kernel_launch(void* const* d_in, const int* in_sizes, int n_in,
                              void* d_out, int out_size, void* d_ws, size_t ws_size,
                              hipStream_t stream) {
  (void)in_sizes; (void)n_in; (void)out_size; (void)ws_size;
  const float* x  = (const float*)d_in[0];
  const float* Wq = (const float*)d_in[1];
  const float* Wk = (const float*)d_in[2];
  const float* Wv = (const float*)d_in[3];
  const float* Wo = (const float*)d_in[4];

  char* ws = (char*)d_ws;
  char* od = (char*)d_out;
  float* outp = (float*)d_out;

  // d_out hosts qb+kb (raw, un-roped; 32 MiB each); dead before out-proj overwrites.
  __bf16* qb = (__bf16*)(od);
  __bf16* kb = (__bf16*)(od + 33554432);
  // ws: xb/aob @0 (32M), vtb @32M (32M), wqkv @64M (6M), wob @70M (2M), tables @72M
  __bf16* xb   = (__bf16*)(ws);
  __bf16* vtb  = (__bf16*)(ws + 33554432);
  __bf16* wqkv = (__bf16*)(ws + 67108864);
  __bf16* wob  = (__bf16*)(ws + 73400320);
  float*  cosT = (float*)(ws + 75497472);
  float*  sinT = (float*)(ws + 75563008);
  __bf16* aob  = xb;  // x dead after QKV GEMM

  auto k0 = gemm8<0>; auto k1 = gemm8<1>;
  hipFuncSetAttribute((const void*)k0, hipFuncAttributeMaxDynamicSharedMemorySize, 131072);
  hipFuncSetAttribute((const void*)k1, hipFuncAttributeMaxDynamicSharedMemorySize, 131072);
  hipFuncSetAttribute((const void*)attn_kernel, hipFuncAttributeMaxDynamicSharedMemorySize, 131584);

  // 1) fused casts + rope tables
  prep_kernel<<<dim3(20544), dim3(256), 0, stream>>>(
      x, Wq, Wk, Wv, Wo, xb, wqkv, wob, cosT, sinT);

  // 2) QKV: M=16384, N=3072 -> 768 blocks (8-phase BK64)
  gemm8<0><<<dim3(768), dim3(512), 131072, stream>>>(
      xb, wqkv, wqkv + 1048576, wqkv + 2097152, qb, kb, vtb, nullptr);

  // 3) attention (LDS-resident K/V, fused rope, batched inner loop)
  attn_kernel<<<dim3(B_ * NH_), dim3(512), 131584, stream>>>(
      qb, kb, vtb, aob, cosT, sinT);

  // 4) out-proj: M=16384, N=1024 -> 256 blocks (8-phase BK64)
  gemm8<1><<<dim3(256), dim3(512), 131072, stream>>>(
      aob, wob, nullptr, nullptr, nullptr, nullptr, nullptr, outp);
}

// Round 14
// 240.795 us; speedup vs baseline: 1.1023x; 1.0187x over previous
//
#include <hip/hip_runtime.h>
#include <hip/hip_bf16.h>
#include <stdint.h>

#define B_  32
#define T_  512
#define C_  1024
#define NH_ 16
#define DH_ 64

typedef __attribute__((ext_vector_type(8))) __bf16 bf16x8;
typedef __attribute__((ext_vector_type(4))) __bf16 bf16x4;
typedef __attribute__((ext_vector_type(4))) float  f32x4;

__device__ __forceinline__ void gload_lds16(const void* g, void* lds) {
  __builtin_amdgcn_global_load_lds(
      (const __attribute__((address_space(1))) void*)(uintptr_t)g,
      (__attribute__((address_space(3))) void*)(uint32_t)(uintptr_t)lds,
      16, 0, 0);
}

// ---------------- fused prep: casts + rope tables (one launch) ----------------
__global__ void prep_kernel(const float* __restrict__ x,
                            const float* __restrict__ Wq, const float* __restrict__ Wk,
                            const float* __restrict__ Wv, const float* __restrict__ Wo,
                            __bf16* __restrict__ xb, __bf16* __restrict__ wqkv,
                            __bf16* __restrict__ wob,
                            float* __restrict__ cosT, float* __restrict__ sinT) {
  int i = blockIdx.x * blockDim.x + threadIdx.x;
  if (i < 4194304) {
    f32x4 v = *(const f32x4*)(x + (size_t)i * 4);
    bf16x4 o;
    o[0] = (__bf16)v[0]; o[1] = (__bf16)v[1]; o[2] = (__bf16)v[2]; o[3] = (__bf16)v[3];
    *(bf16x4*)(xb + (size_t)i * 4) = o;
  } else if (i < 5242880) {
    int j = i - 4194304;
    int w = j >> 18, idx = j & 262143;
    const float* src = (w == 0) ? Wq : (w == 1) ? Wk : (w == 2) ? Wv : Wo;
    __bf16* dst = (w == 3) ? wob : wqkv + (size_t)w * 1048576;
    f32x4 v = *(const f32x4*)(src + (size_t)idx * 4);
    bf16x4 o;
    o[0] = (__bf16)v[0]; o[1] = (__bf16)v[1]; o[2] = (__bf16)v[2]; o[3] = (__bf16)v[3];
    *(bf16x4*)(dst + (size_t)idx * 4) = o;
  } else if (i < 5259264) {
    int j = i - 5242880;            // T_*32
    int t = j >> 5, f = j & 31;
    float inv = powf(10000.0f, -(float)(2 * f) / 64.0f);
    float fr = (float)t * inv;
    cosT[j] = cosf(fr);
    sinT[j] = sinf(fr);
  }
}

// ------------ 256x256 BK64 8-phase counted-vmcnt GEMM (r11, measured best) ---
template <int MODE>
__global__ __launch_bounds__(512, 2) void gemm8(
    const __bf16* __restrict__ A,
    const __bf16* __restrict__ W0, const __bf16* __restrict__ W1, const __bf16* __restrict__ W2,
    __bf16* __restrict__ q, __bf16* __restrict__ k, __bf16* __restrict__ vt,
    float* __restrict__ outp) {
  extern __shared__ __bf16 lds[];
  const int K = C_;
  const int NH8 = 64;   // (K/64) tiles * 4 halves
  int tid = threadIdx.x;
  int lane = tid & 63, wave = tid >> 6;
  int ql = lane & 15, g = lane >> 4;
  int wr = wave >> 2, wc = wave & 3;

  constexpr int BNH = (MODE == 0) ? 6 : 2;   // bn per XCD (r6 L2-aware map)
  int bid = blockIdx.x;
  int xcd = bid & 7, local = bid >> 3;
  int bm = (xcd >> 1) * 16 + local / BNH;
  int bn = (xcd & 1) * BNH + local % BNH;

  const __bf16* Ag = A + (size_t)bm * 256 * K;
  const __bf16* Wg;
  if (MODE == 0) {
    int mat = bn >> 2;
    const __bf16* Wsel = (mat == 0) ? W0 : (mat == 1) ? W1 : W2;
    Wg = Wsel + (size_t)(bn & 3) * 256 * K;
  } else {
    Wg = W0 + (size_t)bn * 256 * K;
  }

  int schunk = (tid & 3) ^ ((tid >> 3) & 3);
  size_t stg_base = (size_t)(tid >> 2) * K + schunk * 8;

  int xsw = (g ^ ((ql >> 1) & 3)) * 8;
  int aoffW[8], boffW[4];
#pragma unroll
  for (int m = 0; m < 8; m++) aoffW[m] = (wr * 128 + m * 16 + ql) * 32 + xsw;
#pragma unroll
  for (int n = 0; n < 4; n++) boffW[n] = (wc * 64 + n * 16 + ql) * 32 + xsw;

#define STAGE_H(h)                                                          \
  if ((h) < NH8) {                                                          \
    int tl_ = (h) >> 2, pt_ = (h) & 3;                                      \
    const __bf16* s_ = ((pt_ & 1) ? Wg : Ag) + stg_base +                   \
                       (size_t)tl_ * 64 + (pt_ >> 1) * 32;                  \
    __bf16* d_ = lds + (((tl_ & 1) * 4 + pt_) * 8192) + tid * 8;            \
    gload_lds16(s_, d_);                                                    \
    gload_lds16(s_ + (size_t)128 * K, d_ + 4096);                           \
  }

#define PH(TP, KK, MLO, RB, SH, VM)                                         \
  {                                                                         \
    const __bf16* abase_ = lds + (((TP) * 4 + ((KK) ? 2 : 0)) * 8192);      \
    _Pragma("unroll")                                                       \
    for (int mm = 0; mm < 4; mm++)                                          \
      a[mm] = *(const bf16x8*)(abase_ + aoffW[(MLO) + mm]);                 \
    if (RB) {                                                               \
      const __bf16* bbase_ = lds + (((TP) * 4 + ((KK) ? 3 : 1)) * 8192);    \
      _Pragma("unroll")                                                     \
      for (int n = 0; n < 4; n++)                                           \
        b[n] = *(const bf16x8*)(bbase_ + boffW[n]);                         \
    }                                                                       \
    STAGE_H(SH);                                                            \
    __builtin_amdgcn_s_barrier();                                           \
    asm volatile("s_waitcnt lgkmcnt(0)" ::: "memory");                      \
    __builtin_amdgcn_sched_barrier(0);                                      \
    __builtin_amdgcn_s_setprio(1);                                          \
    _Pragma("unroll")                                                       \
    for (int mm = 0; mm < 4; mm++)                                          \
      _Pragma("unroll")                                                     \
      for (int n = 0; n < 4; n++)                                           \
        acc[(MLO) + mm][n] = __builtin_amdgcn_mfma_f32_16x16x32_bf16(       \
            a[mm], b[n], acc[(MLO) + mm][n], 0, 0, 0);                      \
    __builtin_amdgcn_s_setprio(0);                                          \
    {                                                                       \
      int vm_ = (VM);                                                       \
      if (vm_ == 0)      { asm volatile("s_waitcnt vmcnt(0)" ::: "memory"); } \
      else if (vm_ > 0)  { asm volatile("s_waitcnt vmcnt(6)" ::: "memory"); } \
    }                                                                       \
    __builtin_amdgcn_s_barrier();                                           \
  }

  STAGE_H(0); STAGE_H(1); STAGE_H(2); STAGE_H(3);
  STAGE_H(4); STAGE_H(5); STAGE_H(6);
  asm volatile("s_waitcnt vmcnt(6)" ::: "memory");
  __builtin_amdgcn_s_barrier();
  __builtin_amdgcn_sched_barrier(0);

  f32x4 acc[8][4] = {};
  bf16x8 a[4], b[4];
  for (int i = 0; i < 8; ++i) {
    int hb = 8 * i;
    int vm4 = (i == 7) ? 0 : 6;
    int vm8 = (i == 7) ? -1 : 6;
    PH(0, 0, 0, 1, hb + 7,  -1)
    PH(0, 0, 4, 0, hb + 8,  -1)
    PH(0, 1, 0, 1, hb + 9,  -1)
    PH(0, 1, 4, 0, hb + 10, vm4)
    PH(1, 0, 0, 1, hb + 11, -1)
    PH(1, 0, 4, 0, hb + 12, -1)
    PH(1, 1, 0, 1, hb + 13, -1)
    PH(1, 1, 4, 0, hb + 14, vm8)
  }
#undef PH
#undef STAGE_H

  int r0 = bm * 256 + wr * 128;
  int c0 = bn * 256 + wc * 64;
  if (MODE == 0) {
    int mat = c0 >> 10;  // block-uniform
#pragma unroll
    for (int m = 0; m < 8; m++) {
      int row = r0 + m * 16 + g * 4;
      int bb = row >> 9, tt = row & 511;
#pragma unroll
      for (int n = 0; n < 4; n++) {
        int col = c0 + n * 16 + ql;
        int h = (col & 1023) >> 6, d = col & 63;
        if (mat == 2) {
          bf16x4 ov;
#pragma unroll
          for (int r = 0; r < 4; r++) ov[r] = (__bf16)acc[m][n][r];
          *(bf16x4*)(vt + ((size_t)(bb * NH_ + h) * DH_ + d) * T_ + tt) = ov;
        } else {
          __bf16* dst = (mat == 0 ? q : k) + ((size_t)(bb * NH_ + h) * T_ + tt) * DH_ + d;
#pragma unroll
          for (int r = 0; r < 4; r++) dst[r * DH_] = (__bf16)acc[m][n][r];
        }
      }
    }
  } else {
#pragma unroll
    for (int m = 0; m < 8; m++) {
      int row = r0 + m * 16 + g * 4;
#pragma unroll
      for (int r = 0; r < 4; r++)
#pragma unroll
        for (int n = 0; n < 4; n++)
          outp[(size_t)(row + r) * C_ + c0 + n * 16 + ql] = acc[m][n][r];
    }
  }
}

// ---------------- flash attention: 1024-thread block (16 waves, 4/SIMD) -----
// r13 memory layouts and per-row math unchanged; r14: 16 waves x 32 q-rows
// each (TLP 2->4 waves/SIMD to hide staging + softmax-shfl latency). Per-wave
// state halves (~110 VGPR, under the 128 cap required by 1024-thread blocks).
// vf ds_reads moved after QK MFMAs (kf dead before vf live -> lower peak regs).
__global__ __launch_bounds__(1024) void attn_kernel(
    const __bf16* __restrict__ qg, const __bf16* __restrict__ kg,
    const __bf16* __restrict__ vg, __bf16* __restrict__ ao,
    const float* __restrict__ cosT, const float* __restrict__ sinT) {
  extern __shared__ char smem[];
  __bf16* Klds = (__bf16*)smem;              // [512][64], chunk-XOR swizzled
  __bf16* Vlds = (__bf16*)(smem + 65536);    // [64][516] padded

  int tid = threadIdx.x;
  int lane = tid & 63, wave = tid >> 6;      // wave 0..15
  int ql = lane & 15, g = lane >> 4;
  int bh = blockIdx.x;
  int b = bh >> 4, h = bh & 15;
  const __bf16* qp = qg + (size_t)bh * (T_ * DH_);
  const __bf16* kp = kg + (size_t)bh * (T_ * DH_);
  const __bf16* vp = vg + (size_t)bh * (T_ * DH_);  // [DH][T]

  // ---- stage K (with rope): 1024 threads x 4 rows ----
  {
    int cb = tid & 7;       // 16B chunk within row
    int rb = tid >> 3;      // row base 0..127
#pragma unroll
    for (int i = 0; i < 4; i++) {
      int row = rb + i * 128;
      bf16x8 raw = *(const bf16x8*)(kp + (size_t)row * DH_ + cb * 8);
      f32x4 c4 = *(const f32x4*)(cosT + row * 32 + cb * 4);
      f32x4 s4 = *(const f32x4*)(sinT + row * 32 + cb * 4);
      bf16x8 out;
#pragma unroll
      for (int p = 0; p < 4; p++) {
        float a0 = (float)raw[2 * p], a1 = (float)raw[2 * p + 1];
        out[2 * p]     = (__bf16)(a0 * c4[p] - a1 * s4[p]);
        out[2 * p + 1] = (__bf16)(a0 * s4[p] + a1 * c4[p]);
      }
      *(bf16x8*)(Klds + row * 64 + ((cb ^ (row & 7)) * 8)) = out;
    }
  }
  // ---- stage V^T (linear, padded rows): 1024 threads x 4 chunks ----
  {
    int d = tid >> 4;          // 0..63
    int cb = tid & 15;
    const __bf16* vrow = vp + (size_t)d * T_;
#pragma unroll
    for (int i = 0; i < 4; i++) {
      int c8 = cb + i * 16;    // 16B chunk 0..63 within row
      bf16x8 raw = *(const bf16x8*)(vrow + c8 * 8);
      *(bf16x8*)(Vlds + d * 516 + c8 * 8) = raw;
    }
  }

  // ---- load + rope Q (scale 1/8): 2 s-slots per wave ----
  int q0 = wave * 32;
  bf16x8 qf[2][2];
#pragma unroll
  for (int s = 0; s < 2; s++)
#pragma unroll
    for (int kk = 0; kk < 2; kk++) {
      int tq = q0 + s * 16 + ql;
      bf16x8 raw = *(const bf16x8*)(qp + (size_t)tq * DH_ + kk * 32 + g * 8);
      int fb = tq * 32 + kk * 16 + g * 4;
      f32x4 c4 = *(const f32x4*)(cosT + fb);
      f32x4 s4 = *(const f32x4*)(sinT + fb);
      bf16x8 out;
#pragma unroll
      for (int p = 0; p < 4; p++) {
        float a0 = (float)raw[2 * p], a1 = (float)raw[2 * p + 1];
        out[2 * p]     = (__bf16)(0.125f * (a0 * c4[p] - a1 * s4[p]));
        out[2 * p + 1] = (__bf16)(0.125f * (a0 * s4[p] + a1 * c4[p]));
      }
      qf[s][kk] = out;
    }

  __syncthreads();

  f32x4 o[2][4] = {};
  float mrow[2] = {-1e30f, -1e30f};
  float lrow[2] = {0.f, 0.f};

  for (int kv0 = 0; kv0 < T_; kv0 += 32) {
    // K fragments for this tile
    bf16x8 kf[2][2];
#pragma unroll
    for (int sub = 0; sub < 2; sub++)
#pragma unroll
      for (int kk = 0; kk < 2; kk++) {
        int t = kv0 + sub * 16 + ql;
        int cc = kk * 4 + g;
        kf[sub][kk] = *(const bf16x8*)(Klds + t * 64 + ((cc ^ (t & 7)) * 8));
      }

    // ---- 1) QK^T for both s (one MFMA region) ----
    f32x4 sa[2], sb[2];
    __builtin_amdgcn_s_setprio(1);
#pragma unroll
    for (int s = 0; s < 2; s++) {
      sa[s] = (f32x4){0.f, 0.f, 0.f, 0.f};
      sb[s] = (f32x4){0.f, 0.f, 0.f, 0.f};
#pragma unroll
      for (int kk = 0; kk < 2; kk++) {
        sa[s] = __builtin_amdgcn_mfma_f32_16x16x32_bf16(kf[0][kk], qf[s][kk], sa[s], 0, 0, 0);
        sb[s] = __builtin_amdgcn_mfma_f32_16x16x32_bf16(kf[1][kk], qf[s][kk], sb[s], 0, 0, 0);
      }
    }
    __builtin_amdgcn_s_setprio(0);

    // V fragments (after QK: kf dead, vf live -> lower peak registers)
    bf16x8 vf[4];
#pragma unroll
    for (int c = 0; c < 4; c++) {
      int d = c * 16 + ql;
      bf16x4 vlo = *(const bf16x4*)(Vlds + d * 516 + kv0 + g * 4);
      bf16x4 vhi = *(const bf16x4*)(Vlds + d * 516 + kv0 + 16 + g * 4);
#pragma unroll
      for (int r = 0; r < 4; r++) { vf[c][r] = vlo[r]; vf[c][4 + r] = vhi[r]; }
    }

    // ---- 2) tile max per s ----
    float tm[2];
#pragma unroll
    for (int s = 0; s < 2; s++) {
      float t0 = fmaxf(fmaxf(sa[s][0], sa[s][1]), fmaxf(sa[s][2], sa[s][3]));
      float t1 = fmaxf(fmaxf(sb[s][0], sb[s][1]), fmaxf(sb[s][2], sb[s][3]));
      tm[s] = fmaxf(t0, t1);
    }
#pragma unroll
    for (int s = 0; s < 2; s++) tm[s] = fmaxf(tm[s], __shfl_xor(tm[s], 16));
#pragma unroll
    for (int s = 0; s < 2; s++) tm[s] = fmaxf(tm[s], __shfl_xor(tm[s], 32));

    // ---- 3) single deferred-rescale branch (THR=8, exact math) ----
    bool need = (tm[0] > mrow[0] + 8.f) | (tm[1] > mrow[1] + 8.f);
    if (__any(need)) {
#pragma unroll
      for (int s = 0; s < 2; s++) {
        float mnew = fmaxf(mrow[s], tm[s]);
        float corr = __expf(mrow[s] - mnew);
        mrow[s] = mnew;
        lrow[s] *= corr;
#pragma unroll
        for (int c = 0; c < 4; c++) o[s][c] *= corr;
      }
    }

    // ---- 4) exp in place + row sums ----
    float ps[2];
#pragma unroll
    for (int s = 0; s < 2; s++) {
#pragma unroll
      for (int r = 0; r < 4; r++) {
        sa[s][r] = __expf(sa[s][r] - mrow[s]);
        sb[s][r] = __expf(sb[s][r] - mrow[s]);
      }
      ps[s] = ((sa[s][0] + sa[s][1]) + (sa[s][2] + sa[s][3])) +
              ((sb[s][0] + sb[s][1]) + (sb[s][2] + sb[s][3]));
    }
#pragma unroll
    for (int s = 0; s < 2; s++) ps[s] += __shfl_xor(ps[s], 16);
#pragma unroll
    for (int s = 0; s < 2; s++) { ps[s] += __shfl_xor(ps[s], 32); lrow[s] += ps[s]; }

    // ---- 5) P->bf16 + PV MFMAs (one region) ----
    bf16x8 pb[2];
#pragma unroll
    for (int s = 0; s < 2; s++)
#pragma unroll
      for (int r = 0; r < 4; r++) {
        pb[s][r]     = (__bf16)sa[s][r];
        pb[s][4 + r] = (__bf16)sb[s][r];
      }
    __builtin_amdgcn_s_setprio(1);
#pragma unroll
    for (int s = 0; s < 2; s++)
#pragma unroll
      for (int c = 0; c < 4; c++)
        o[s][c] = __builtin_amdgcn_mfma_f32_16x16x32_bf16(vf[c], pb[s], o[s][c], 0, 0, 0);
    __builtin_amdgcn_s_setprio(0);
  }

#pragma unroll
  for (int s = 0; s < 2; s++) {
    float inv = 1.0f / lrow[s];
    size_t row = (size_t)b * T_ + q0 + s * 16 + ql;
    size_t baseo = row * C_ + h * DH_;
#pragma unroll
    for (int c = 0; c < 4; c++) {
      bf16x4 ov;
#pragma unroll
      for (int r = 0; r < 4; r++) ov[r] = (__bf16)(o[s][c][r] * inv);
      *(bf16x4*)(ao + baseo + c * 16 + g * 4) = ov;
    }
  }
}

extern "C" void kernel_launch(void* const* d_in, const int* in_sizes, int n_in,
                              void* d_out, int out_size, void* d_ws, size_t ws_size,
                              hipStream_t stream) {
  (void)in_sizes; (void)n_in; (void)out_size; (void)ws_size;
  const float* x  = (const float*)d_in[0];
  const float* Wq = (const float*)d_in[1];
  const float* Wk = (const float*)d_in[2];
  const float* Wv = (const float*)d_in[3];
  const float* Wo = (const float*)d_in[4];

  char* ws = (char*)d_ws;
  char* od = (char*)d_out;
  float* outp = (float*)d_out;

  // d_out hosts qb+kb (raw, un-roped; 32 MiB each); dead before out-proj overwrites.
  __bf16* qb = (__bf16*)(od);
  __bf16* kb = (__bf16*)(od + 33554432);
  // ws: xb/aob @0 (32M), vtb @32M (32M), wqkv @64M (6M), wob @70M (2M), tables @72M
  __bf16* xb   = (__bf16*)(ws);
  __bf16* vtb  = (__bf16*)(ws + 33554432);
  __bf16* wqkv = (__bf16*)(ws + 67108864);
  __bf16* wob  = (__bf16*)(ws + 73400320);
  float*  cosT = (float*)(ws + 75497472);
  float*  sinT = (float*)(ws + 75563008);
  __bf16* aob  = xb;  // x dead after QKV GEMM

  auto k0 = gemm8<0>; auto k1 = gemm8<1>;
  hipFuncSetAttribute((const void*)k0, hipFuncAttributeMaxDynamicSharedMemorySize, 131072);
  hipFuncSetAttribute((const void*)k1, hipFuncAttributeMaxDynamicSharedMemorySize, 131072);
  hipFuncSetAttribute((const void*)attn_kernel, hipFuncAttributeMaxDynamicSharedMemorySize, 131584);

  // 1) fused casts + rope tables
  prep_kernel<<<dim3(20544), dim3(256), 0, stream>>>(
      x, Wq, Wk, Wv, Wo, xb, wqkv, wob, cosT, sinT);

  // 2) QKV: M=16384, N=3072 -> 768 blocks (8-phase BK64)
  gemm8<0><<<dim3(768), dim3(512), 131072, stream>>>(
      xb, wqkv, wqkv + 1048576, wqkv + 2097152, qb, kb, vtb, nullptr);

  // 3) attention (LDS-resident K/V, fused rope, 1024-thread blocks)
  attn_kernel<<<dim3(B_ * NH_), dim3(1024), 131584, stream>>>(
      qb, kb, vtb, aob, cosT, sinT);

  // 4) out-proj: M=16384, N=1024 -> 256 blocks (8-phase BK64)
  gemm8<1><<<dim3(256), dim3(512), 131072, stream>>>(
      aob, wob, nullptr, nullptr, nullptr, nullptr, nullptr, outp);
}